// Round 3
// baseline (83.619 us; speedup 1.0000x reference)
//
#include <hip/hip_runtime.h>

#define NB 4      // B
#define NS 512    // S
#define NSC 128   // SC
#define NMC 64    // MC
#define NR 32     // R
#define NO 64     // O
#define NHID 256  // 4*O

typedef float f4 __attribute__((ext_vector_type(4)));

__device__ __forceinline__ float wave_sum(float v) {
    #pragma unroll
    for (int m = 1; m < 64; m <<= 1) v += __shfl_xor(v, m, 64);
    return v;
}
__device__ __forceinline__ float wave_max(float v) {
    #pragma unroll
    for (int m = 1; m < 64; m <<= 1) v = fmaxf(v, __shfl_xor(v, m, 64));
    return v;
}

// --- K1: q,k projections: one block (64 thr) per (b,s) row --------------
__global__ __launch_bounds__(64) void qk_kernel(
    const float* __restrict__ seq,
    const float* __restrict__ Wq, const float* __restrict__ bq,
    const float* __restrict__ Wk, const float* __restrict__ bk,
    float* __restrict__ q, float* __restrict__ k) {
    int bs  = blockIdx.x;
    int tid = threadIdx.x;
    __shared__ float srow[NSC];
    const float* sp = seq + (size_t)bs * NSC;
    srow[tid]      = sp[tid];
    srow[tid + 64] = sp[tid + 64];
    __syncthreads();
    int r = tid & 31;
    const float* W    = (tid < 32) ? Wq : Wk;
    const float* bias = (tid < 32) ? bq : bk;
    float acc = bias[r];
    #pragma unroll 8
    for (int c = 0; c < NSC; ++c) acc += srow[c] * W[c * NR + r];
    float* dst = (tid < 32) ? q : k;
    dst[(size_t)bs * NR + r] = acc;
}

// --- K2: softmax attention rows -> ws (one block per (b,s), 256 thr) ----
__global__ __launch_bounds__(256) void attn_kernel(
    const float* __restrict__ q, const float* __restrict__ k,
    float* __restrict__ attn) {
    const float DENOM_INV = 0.17677669529663687f;  // 1/sqrt(32)
    int bs   = blockIdx.x;
    int b    = bs >> 9;
    int tid  = threadIdx.x;
    int lane = tid & 63;
    int wave = tid >> 6;

    __shared__ float s_q[NR];
    __shared__ float s_red[8];
    if (tid < NR) s_q[tid] = q[(size_t)bs * NR + tid];
    __syncthreads();

    const float* kb = k + (size_t)b * NS * NR;
    const f4* q4 = (const f4*)s_q;
    const f4* k0 = (const f4*)(kb + (size_t)tid * NR);
    const f4* k1 = (const f4*)(kb + (size_t)(tid + 256) * NR);
    float a0 = 0.f, a1 = 0.f;
    #pragma unroll
    for (int r4 = 0; r4 < NR / 4; ++r4) {
        f4 qv = q4[r4], kv0 = k0[r4], kv1 = k1[r4];
        a0 += qv.x * kv0.x + qv.y * kv0.y + qv.z * kv0.z + qv.w * kv0.w;
        a1 += qv.x * kv1.x + qv.y * kv1.y + qv.z * kv1.z + qv.w * kv1.w;
    }
    float lg0 = a0 * DENOM_INV, lg1 = a1 * DENOM_INV;

    float mx = wave_max(fmaxf(lg0, lg1));
    if (lane == 0) s_red[wave] = mx;
    __syncthreads();
    mx = fmaxf(fmaxf(s_red[0], s_red[1]), fmaxf(s_red[2], s_red[3]));
    float e0 = expf(lg0 - mx), e1 = expf(lg1 - mx);
    float ssum = wave_sum(e0 + e1);
    if (lane == 0) s_red[4 + wave] = ssum;
    __syncthreads();
    float inv = 1.f / (s_red[4] + s_red[5] + s_red[6] + s_red[7]);
    float* ap = attn + (size_t)bs * NS;
    ap[tid]       = e0 * inv;
    ap[tid + 256] = e1 * inv;
}

// --- K3: pure map_ stream: m[b,s,d] = sum_t attn[b,s,t]*map_[b,d,s,t] ---
// 8192 blocks: bs = bid & 2047, dblk = bid >> 11 (same-XCD reuse of attn
// row across the 4 rounds). 256 thr; wave w owns d = dblk*16 + w*4 .. +3.
__global__ __launch_bounds__(256) void pool_kernel(
    const float* __restrict__ map_, const float* __restrict__ attn,
    float* __restrict__ m) {
    int bid  = blockIdx.x;
    int bs   = bid & 2047;
    int dblk = bid >> 11;
    int b    = bs >> 9;
    int s    = bs & 511;
    int tid  = threadIdx.x;
    int lane = tid & 63;
    int wave = tid >> 6;

    __shared__ float s_part[16][65];

    const f4* attn4 = (const f4*)(attn + (size_t)bs * NS);
    f4 w0 = attn4[lane];
    f4 w1 = attn4[lane + 64];

    int d0 = dblk * 16 + wave * 4;
    const f4* base = (const f4*)(map_ + (((size_t)b * NMC + d0) * NS + s) * NS);
    #pragma unroll
    for (int i = 0; i < 4; ++i) {
        const f4* rp = base + (size_t)i * (NS * NS / 4);
        f4 a0 = __builtin_nontemporal_load(rp + lane);
        f4 a1 = __builtin_nontemporal_load(rp + lane + 64);
        float acc0 = a0.x * w0.x + a0.y * w0.y + a0.z * w0.z + a0.w * w0.w;
        float acc1 = a1.x * w1.x + a1.y * w1.y + a1.z * w1.z + a1.w * w1.w;
        s_part[wave * 4 + i][lane] = acc0 + acc1;
    }
    __syncthreads();

    if (tid < 16) {
        float acc = 0.f;
        #pragma unroll 8
        for (int j = 0; j < 64; ++j) acc += s_part[tid][j];
        m[(size_t)bs * NMC + dblk * 16 + tid] = acc;
    }
}

// --- K4: tail: pooled = m@Wv+bv, LN, MLP (one block per (b,s), 256 thr) -
__global__ __launch_bounds__(256) void tail_kernel(
    const float* __restrict__ m,
    const float* __restrict__ Wv, const float* __restrict__ bv,
    const float* __restrict__ gamma, const float* __restrict__ beta,
    const float* __restrict__ W1, const float* __restrict__ b1,
    const float* __restrict__ W2, const float* __restrict__ b2,
    float* __restrict__ out) {
    const float LN_EPS = 1e-5f;
    int bs  = blockIdx.x;
    int tid = threadIdx.x;
    int c    = tid & 63;
    int part = tid >> 6;

    __shared__ float s_m[NMC];
    __shared__ float s_score[NMC];
    __shared__ float s_h[NHID];
    __shared__ float s_p[4][65];

    if (tid < NMC) s_m[tid] = m[(size_t)bs * NMC + tid];
    __syncthreads();

    // pooled = m @ Wv + bv, split-K over 4 waves
    {
        float acc = 0.f;
        #pragma unroll
        for (int i = 0; i < 16; ++i) {
            int d = part * 16 + i;
            acc += s_m[d] * Wv[d * NMC + c];
        }
        s_p[part][c] = acc;
    }
    __syncthreads();

    if (tid < NMC) {
        float pooled = bv[tid] + s_p[0][tid] + s_p[1][tid] + s_p[2][tid] + s_p[3][tid];
        float sum   = wave_sum(pooled);
        float sumsq = wave_sum(pooled * pooled);
        float mu  = sum * (1.f / NMC);
        float var = sumsq * (1.f / NMC) - mu * mu;
        float rsig = rsqrtf(var + LN_EPS);
        s_score[tid] = (pooled - mu) * rsig * gamma[tid] + beta[tid];
    }
    __syncthreads();

    // h = relu(score @ W1 + b1): thread tid owns hidden unit tid
    {
        float hacc = b1[tid];
        #pragma unroll 8
        for (int cc = 0; cc < NMC; ++cc) hacc += s_score[cc] * W1[cc * NHID + tid];
        s_h[tid] = fmaxf(hacc, 0.f);
    }
    __syncthreads();

    // out = h @ W2 + b2, split-K over 4 waves
    {
        float acc = 0.f;
        #pragma unroll
        for (int i = 0; i < 64; ++i) {
            int j = part * 64 + i;
            acc += s_h[j] * W2[j * NO + c];
        }
        s_p[part][c] = acc;
    }
    __syncthreads();

    if (tid < NO)
        out[(size_t)bs * NO + tid] =
            b2[tid] + s_p[0][tid] + s_p[1][tid] + s_p[2][tid] + s_p[3][tid];
}

extern "C" void kernel_launch(void* const* d_in, const int* in_sizes, int n_in,
                              void* d_out, int out_size, void* d_ws, size_t ws_size,
                              hipStream_t stream) {
    const float* map_  = (const float*)d_in[0];
    const float* seq   = (const float*)d_in[1];
    const float* Wq    = (const float*)d_in[2];
    const float* bq    = (const float*)d_in[3];
    const float* Wk    = (const float*)d_in[4];
    const float* bk    = (const float*)d_in[5];
    const float* Wv    = (const float*)d_in[6];
    const float* bv    = (const float*)d_in[7];
    const float* gamma = (const float*)d_in[8];
    const float* beta  = (const float*)d_in[9];
    const float* W1    = (const float*)d_in[10];
    const float* b1    = (const float*)d_in[11];
    const float* W2    = (const float*)d_in[12];
    const float* b2    = (const float*)d_in[13];
    float* out = (float*)d_out;

    float* q    = (float*)d_ws;                        // B*S*R
    float* kk   = q    + (size_t)NB * NS * NR;         // B*S*R
    float* attn = kk   + (size_t)NB * NS * NR;         // B*S*S
    float* m    = attn + (size_t)NB * NS * NS;         // B*S*MC

    qk_kernel  <<<NB * NS,     64, 0, stream>>>(seq, Wq, bq, Wk, bk, q, kk);
    attn_kernel<<<NB * NS,    256, 0, stream>>>(q, kk, attn);
    pool_kernel<<<NB * NS * 4, 256, 0, stream>>>(map_, attn, m);
    tail_kernel<<<NB * NS,    256, 0, stream>>>(m, Wv, bv, gamma, beta,
                                                W1, b1, W2, b2, out);
}